// Round 8
// baseline (747.578 us; speedup 1.0000x reference)
//
#include <hip/hip_runtime.h>
#include <hip/hip_cooperative_groups.h>

namespace cg = cooperative_groups;

#define B_     16
#define N_IN_  6250
#define N_OUT_ 25000
#define C_     64
#define S_     9
#define NNZ_   75000
#define MT2_   98           // ceil(N_OUT/256)

#define PREP_GRID  512
#define PREP_BLOCK 512
#define PREP_THREADS (PREP_GRID * PREP_BLOCK)

typedef __bf16 bf16x8 __attribute__((ext_vector_type(8)));
typedef float floatx4 __attribute__((ext_vector_type(4)));

__device__ inline void async_copy16(const void* g, void* l) {
    __builtin_amdgcn_global_load_lds(
        (const __attribute__((address_space(1))) void*)g,
        (__attribute__((address_space(3))) void*)l, 16, 0, 0);
}

// ---------------- fused prep: zero+convw -> hist -> scan -> fill -> pool ----
// ONE cooperative kernel replaces 8 graph nodes (memset, hist, scan1/2/3,
// fill, convw, pool) to eliminate per-node launch overhead (~10us each).
// grid 512 x 512 (2 blocks/CU co-resident, trivially valid for coop launch).
__global__ __launch_bounds__(PREP_BLOCK, 4) void prep_kernel(
        const float* __restrict__ x, const int* __restrict__ trow,
        const int* __restrict__ tcol, const float* __restrict__ tvals,
        const float* __restrict__ W,
        int* __restrict__ counts, int* __restrict__ offsets,
        int* __restrict__ cursor, int* __restrict__ ecol,
        float* __restrict__ eval, __bf16* __restrict__ WtF,
        __bf16* __restrict__ pooled) {
    cg::grid_group grid = cg::this_grid();
    int t = threadIdx.x;
    int gid = blockIdx.x * PREP_BLOCK + t;

    // ---- phase 0: zero counts + build WtF (independent) ----
    for (int i = gid; i < N_OUT_; i += PREP_THREADS) counts[i] = 0;
    for (int i = gid; i < 72 * 64 * 8; i += PREP_THREADS) {
        int kb = i >> 9;
        int n  = (i >> 3) & 63;
        int j  = i & 7;
        WtF[i] = (__bf16)W[(kb * 8 + j) * 64 + n];
    }
    __threadfence();
    grid.sync();

    // ---- phase 1: histogram of trans_row ----
    for (int i = gid; i < NNZ_; i += PREP_THREADS)
        atomicAdd(&counts[trow[i]], 1);
    __threadfence();
    grid.sync();

    // ---- phase 2: exclusive scan (block 0 only, 49 chunks of 512) ----
    if (blockIdx.x == 0) {
        __shared__ int wsum[8];
        __shared__ int carry;
        int wid = t >> 6, lane = t & 63;
        if (t == 0) carry = 0;
        __syncthreads();
        for (int base = 0; base < N_OUT_; base += PREP_BLOCK) {
            int i = base + t;
            int v = (i < N_OUT_) ? counts[i] : 0;
            int s = v;
            #pragma unroll
            for (int d = 1; d < 64; d <<= 1) {
                int u = __shfl_up(s, d, 64);
                if (lane >= d) s += u;
            }
            if (lane == 63) wsum[wid] = s;
            __syncthreads();
            if (wid == 0 && lane < 8) {
                int ws = wsum[lane];
                #pragma unroll
                for (int d = 1; d < 8; d <<= 1) {
                    int u = __shfl_up(ws, d, 64);
                    if (lane >= d) ws += u;
                }
                wsum[lane] = ws;
            }
            __syncthreads();
            int wave_off = (wid == 0) ? 0 : wsum[wid - 1];
            int incl = s + wave_off + carry;
            if (i < N_OUT_) {
                int o = incl - v;
                offsets[i] = o;
                cursor[i] = o;
            }
            __syncthreads();               // all carry reads done
            if (t == PREP_BLOCK - 1) carry = incl;
            __syncthreads();
        }
        if (t == 0) offsets[N_OUT_] = carry;
    }
    __threadfence();
    grid.sync();

    // ---- phase 3: fill CSR ----
    for (int i = gid; i < NNZ_; i += PREP_THREADS) {
        int p = atomicAdd(&cursor[trow[i]], 1);
        ecol[p] = tcol[i];
        eval[p] = tvals[i];
    }
    __threadfence();
    grid.sync();

    // ---- phase 4: pooling (round-2 proven wave-per-row, grid-stride) ----
    {
        int wid = t >> 6, lane = t & 63;
        int gw = blockIdx.x * (PREP_BLOCK / 64) + wid;   // 0..4095
        const int NWAVES = PREP_GRID * (PREP_BLOCK / 64);
        int b = lane >> 2;
        int cq = (lane & 3) << 4;
        const float* xb = x + (size_t)b * N_IN_ * C_ + cq;

        for (int row = gw; row < N_OUT_; row += NWAVES) {
            int beg = offsets[row], end = offsets[row + 1];
            floatx4 acc[4] = {};
            int col = 0; float v = 0.f;
            if (beg < end) { col = ecol[beg]; v = eval[beg]; }
            for (int k = beg; k < end; ++k) {
                int col2 = 0; float v2 = 0.f;
                if (k + 1 < end) { col2 = ecol[k + 1]; v2 = eval[k + 1]; }
                const floatx4* xp = reinterpret_cast<const floatx4*>(xb + (size_t)col * C_);
                #pragma unroll
                for (int j = 0; j < 4; ++j) acc[j] += xp[j] * v;
                col = col2; v = v2;
            }
            __bf16* op = pooled + ((size_t)b * N_OUT_ + row) * C_ + cq;
            bf16x8 o0, o1;
            #pragma unroll
            for (int j = 0; j < 4; ++j) {
                o0[j]     = (__bf16)acc[0][j];
                o0[j + 4] = (__bf16)acc[1][j];
                o1[j]     = (__bf16)acc[2][j];
                o1[j + 4] = (__bf16)acc[3][j];
            }
            *reinterpret_cast<bf16x8*>(op)     = o0;
            *reinterpret_cast<bf16x8*>(op + 8) = o1;
        }
    }
}

// ---------------- spiral gather + GEMM + bias + ELU (round-6 verbatim) ------
// grid 1D = 8 * (2*MT2_), XCD-affine: bx&7 = xcd, one batch per block ->
// per-XCD pooled working set 3.2MB (L2-resident, FETCH ~43MB measured).
// Nontemporal out-stores keep the 102MB f32 stream from thrashing L2.
// A-prefetch depth 3 (4 rotating buffers, compile-time select).
__global__ __launch_bounds__(256, 2) void gemm_kernel(
        const __bf16* __restrict__ pooled, const int* __restrict__ spiral,
        const __bf16* __restrict__ WtF, const float* __restrict__ bias,
        float* __restrict__ out) {
    __shared__ __bf16 Bs[72 * 64 * 8];   // 73728 B -> 2 blocks/CU

    int bx = blockIdx.x;
    int xcd = bx & 7;
    int rr = bx >> 3;                    // 0..2*MT2_-1
    int half = (rr >= MT2_) ? 1 : 0;
    int mt = rr - half * MT2_;           // 0..97
    int b = xcd + 8 * half;

    int t = threadIdx.x;
    int wave = t >> 6, lane = t & 63;
    int quad = lane >> 4, l16 = lane & 15;
    int mbase = mt * 256 + wave * 64;

    // stage WtF -> Bs, lane-linear 16B chunks (4608 total, 18/thread)
    #pragma unroll
    for (int j = 0; j < 18; ++j) {
        int idx = t + j * 256;
        async_copy16((const char*)WtF + (size_t)idx * 16, (char*)Bs + idx * 16);
    }

    // per-lane spiral indices for the 4 m-subtiles, vectorized 4+4+1
    int src[4][S_];
    #pragma unroll
    for (int mi = 0; mi < 4; ++mi) {
        int m = mbase + mi * 16 + l16;
        int mc = (m < N_OUT_) ? m : 0;
        const int* sp = spiral + (size_t)mc * S_;
        int4 a0 = *reinterpret_cast<const int4*>(sp);
        int4 a1 = *reinterpret_cast<const int4*>(sp + 4);
        src[mi][0] = a0.x; src[mi][1] = a0.y; src[mi][2] = a0.z; src[mi][3] = a0.w;
        src[mi][4] = a1.x; src[mi][5] = a1.y; src[mi][6] = a1.z; src[mi][7] = a1.w;
        src[mi][8] = sp[8];
    }
    const __bf16* poolb = pooled + (size_t)b * N_OUT_ * C_;

    __syncthreads();   // staging drained (single barrier of the kernel)

    floatx4 acc[4][4] = {};
    bf16x8 A0[4][2], A1[4][2], A2[4][2], A3[4][2];

    auto loadA = [&](int s, bf16x8 (*A)[2]) {
        #pragma unroll
        for (int mi = 0; mi < 4; ++mi) {
            const __bf16* p = poolb + (size_t)src[mi][s] * C_ + quad * 8;
            A[mi][0] = *reinterpret_cast<const bf16x8*>(p);
            A[mi][1] = *reinterpret_cast<const bf16x8*>(p + 32);
        }
    };
    auto bufFor = [&](int s) -> bf16x8 (*)[2] {
        switch (s & 3) {
            case 0:  return A0;
            case 1:  return A1;
            case 2:  return A2;
            default: return A3;
        }
    };

    loadA(0, A0);
    loadA(1, A1);
    loadA(2, A2);
    #pragma unroll
    for (int s = 0; s < S_; ++s) {
        if (s + 3 < S_) {
            loadA(s + 3, bufFor(s + 3));           // depth-3 prefetch
            __builtin_amdgcn_sched_barrier(0);     // pin: loads stay ahead of MFMAs
        }
        bf16x8 (*A)[2] = bufFor(s);
        #pragma unroll
        for (int kc = 0; kc < 2; ++kc) {
            #pragma unroll
            for (int nt = 0; nt < 4; ++nt) {
                int kb = s * 8 + kc * 4 + quad;
                bf16x8 bb = *reinterpret_cast<const bf16x8*>(
                    Bs + (((kb << 6) + (nt << 4) + l16) << 3));
                #pragma unroll
                for (int mi = 0; mi < 4; ++mi)
                    acc[mi][nt] = __builtin_amdgcn_mfma_f32_16x16x32_bf16(
                        A[mi][kc], bb, acc[mi][nt], 0, 0, 0);
            }
        }
    }

    // epilogue: D[m = quad*4 + i][n = l16] per (mi, nt) tile, nontemporal
    float* outb = out + (size_t)b * N_OUT_ * C_;
    #pragma unroll
    for (int mi = 0; mi < 4; ++mi) {
        #pragma unroll
        for (int nt = 0; nt < 4; ++nt) {
            float bn = bias[nt * 16 + l16];
            #pragma unroll
            for (int i = 0; i < 4; ++i) {
                int mm = mbase + mi * 16 + quad * 4 + i;
                if (mm < N_OUT_) {
                    float v = acc[mi][nt][i] + bn;
                    v = (v > 0.0f) ? v : expm1f(v);
                    __builtin_nontemporal_store(v, &outb[(size_t)mm * C_ + nt * 16 + l16]);
                }
            }
        }
    }
}

extern "C" void kernel_launch(void* const* d_in, const int* in_sizes, int n_in,
                              void* d_out, int out_size, void* d_ws, size_t ws_size,
                              hipStream_t stream) {
    const float* x      = (const float*)d_in[0];
    const float* tvals  = (const float*)d_in[1];
    const int*   trow   = (const int*)d_in[2];
    const int*   tcol   = (const int*)d_in[3];
    const int*   spiral = (const int*)d_in[4];
    const float* W      = (const float*)d_in[5];
    const float* bias   = (const float*)d_in[6];
    float* out = (float*)d_out;

    char* ws = (char*)d_ws;
    size_t off = 0;
    auto alloc = [&](size_t bytes) -> void* {
        void* p = ws + off;
        off += (bytes + 255) & ~(size_t)255;
        return p;
    };
    __bf16* pooled  = (__bf16*)alloc((size_t)B_ * N_OUT_ * C_ * 2);   // 51.2 MB
    __bf16* WtF     = (__bf16*)alloc(72 * 64 * 8 * 2);
    int*    cursor  = (int*)alloc(N_OUT_ * 4);
    int*    offsets = (int*)alloc((N_OUT_ + 1) * 4);
    int*    ecol    = (int*)alloc(NNZ_ * 4);
    float*  eval    = (float*)alloc(NNZ_ * 4);
    int*    counts  = (int*)alloc(N_OUT_ * 4);

    void* prep_args[] = {
        (void*)&x, (void*)&trow, (void*)&tcol, (void*)&tvals, (void*)&W,
        (void*)&counts, (void*)&offsets, (void*)&cursor, (void*)&ecol,
        (void*)&eval, (void*)&WtF, (void*)&pooled
    };
    hipLaunchCooperativeKernel((const void*)prep_kernel,
                               dim3(PREP_GRID), dim3(PREP_BLOCK),
                               prep_args, 0, stream);
    gemm_kernel<<<8 * (2 * MT2_), 256, 0, stream>>>(pooled, spiral, WtF, bias, out);
}

// Round 9
// 377.744 us; speedup vs baseline: 1.9791x; 1.9791x over previous
//
#include <hip/hip_runtime.h>

#define B_     16
#define N_IN_  6250
#define N_OUT_ 25000
#define C_     64
#define S_     9
#define NNZ_   75000
#define MT2_   98           // ceil(N_OUT/256)

typedef __bf16 bf16x8 __attribute__((ext_vector_type(8)));
typedef float floatx4 __attribute__((ext_vector_type(4)));

__device__ inline void async_copy16(const void* g, void* l) {
    __builtin_amdgcn_global_load_lds(
        (const __attribute__((address_space(1))) void*)g,
        (__attribute__((address_space(3))) void*)l, 16, 0, 0);
}

// ---------------- init: zero counts + W -> WtF (one node) ----------------
// WtF[(kb*64 + n)*8 + j] = W[(kb*8 + j)*64 + n], kb = k/8 in [0,72).
__global__ void init_kernel(const float* __restrict__ W, __bf16* __restrict__ WtF,
                            int* __restrict__ counts) {
    int i = blockIdx.x * blockDim.x + threadIdx.x;   // over 72*64*8 = 36864
    if (i < N_OUT_) counts[i] = 0;
    if (i < 72 * 64 * 8) {
        int kb = i >> 9;
        int n  = (i >> 3) & 63;
        int j  = i & 7;
        WtF[i] = (__bf16)W[(kb * 8 + j) * 64 + n];
    }
}

// ---------------- CSR build ----------------

__global__ void hist_kernel(const int* __restrict__ rows, int* __restrict__ counts, int nnz) {
    int i = blockIdx.x * blockDim.x + threadIdx.x;
    if (i < nnz) atomicAdd(&counts[rows[i]], 1);
}

// single-block scan over counts -> offsets (+cursor copy); proven in round-3 run
__global__ __launch_bounds__(1024) void scan_kernel(
        const int* __restrict__ counts, int* __restrict__ offsets,
        int* __restrict__ cursor, int n) {
    __shared__ int wsum[16];
    __shared__ int carry;
    int t = threadIdx.x;
    int wid = t >> 6, lane = t & 63;
    if (t == 0) carry = 0;
    __syncthreads();
    for (int base = 0; base < n; base += 1024) {
        int i = base + t;
        int v = (i < n) ? counts[i] : 0;
        int s = v;
        #pragma unroll
        for (int d = 1; d < 64; d <<= 1) {
            int u = __shfl_up(s, d, 64);
            if (lane >= d) s += u;
        }
        if (lane == 63) wsum[wid] = s;
        __syncthreads();
        if (wid == 0 && lane < 16) {
            int ws = wsum[lane];
            #pragma unroll
            for (int d = 1; d < 16; d <<= 1) {
                int u = __shfl_up(ws, d, 64);
                if (lane >= d) ws += u;
            }
            wsum[lane] = ws;
        }
        __syncthreads();
        int wave_off = (wid == 0) ? 0 : wsum[wid - 1];
        int incl = s + wave_off + carry;
        if (i < n) {
            int o = incl - v;
            offsets[i] = o;
            cursor[i] = o;
        }
        __syncthreads();                 // all carry reads done
        if (t == 1023) carry = incl;
        __syncthreads();
    }
    if (t == 0) offsets[n] = carry;
}

__global__ void fill_kernel(const int* __restrict__ rows, const int* __restrict__ cols,
                            const float* __restrict__ vals, int* __restrict__ cursor,
                            int* __restrict__ ecol, float* __restrict__ eval, int nnz) {
    int i = blockIdx.x * blockDim.x + threadIdx.x;
    if (i < nnz) {
        int p = atomicAdd(&cursor[rows[i]], 1);
        ecol[p] = cols[i];
        eval[p] = vals[i];
    }
}

// ---------------- pooling: wave = (batch, row), fully coalesced -------------
// grid 8*12500: bx&7 = xcd -> batches {xcd, xcd+8}; per-XCD x slice 3.2MB =
// L2-resident, and pooled[b] is produced on the XCD whose gemm blocks read it.
// Block = 4 waves = 2 rows x 2 batches. Lane = channel: per nnz the wave
// reads x[b][col][:] = ONE contiguous 256B transaction (vs 16 scattered 64B
// segments before); ecol/eval are wave-uniform scalar loads; store = 128B.
__global__ __launch_bounds__(256) void pool_kernel(
        const float* __restrict__ x, const int* __restrict__ offsets,
        const int* __restrict__ ecol, const float* __restrict__ eval,
        __bf16* __restrict__ pooled) {
    int bx = blockIdx.x;
    int xcd = bx & 7;
    int i = bx >> 3;                       // 0..12499
    int t = threadIdx.x;
    int wid = t >> 6, lane = t & 63;
    int b = xcd + 8 * (wid & 1);
    int row = i * 2 + (wid >> 1);

    const float* xb = x + (size_t)b * N_IN_ * C_ + lane;
    int beg = offsets[row], end = offsets[row + 1];

    float acc = 0.f;
    int col = 0; float v = 0.f;
    if (beg < end) { col = ecol[beg]; v = eval[beg]; }
    for (int k = beg; k < end; ++k) {
        int col2 = 0; float v2 = 0.f;
        if (k + 1 < end) { col2 = ecol[k + 1]; v2 = eval[k + 1]; }
        acc += xb[(size_t)col * C_] * v;
        col = col2; v = v2;
    }
    pooled[((size_t)b * N_OUT_ + row) * C_ + lane] = (__bf16)acc;
}

// ---------------- spiral gather + GEMM + bias + ELU (round-6 verbatim) ------
// grid 1D = 8 * (2*MT2_), XCD-affine: bx&7 = xcd, one batch per block ->
// per-XCD pooled working set 3.2MB (L2-resident, FETCH ~43MB measured).
// Nontemporal out-stores keep the 102MB f32 stream from thrashing L2.
// A-prefetch depth 3 (4 rotating buffers, compile-time select).
__global__ __launch_bounds__(256, 2) void gemm_kernel(
        const __bf16* __restrict__ pooled, const int* __restrict__ spiral,
        const __bf16* __restrict__ WtF, const float* __restrict__ bias,
        float* __restrict__ out) {
    __shared__ __bf16 Bs[72 * 64 * 8];   // 73728 B -> 2 blocks/CU

    int bx = blockIdx.x;
    int xcd = bx & 7;
    int rr = bx >> 3;                    // 0..2*MT2_-1
    int half = (rr >= MT2_) ? 1 : 0;
    int mt = rr - half * MT2_;           // 0..97
    int b = xcd + 8 * half;

    int t = threadIdx.x;
    int wave = t >> 6, lane = t & 63;
    int quad = lane >> 4, l16 = lane & 15;
    int mbase = mt * 256 + wave * 64;

    // stage WtF -> Bs, lane-linear 16B chunks (4608 total, 18/thread)
    #pragma unroll
    for (int j = 0; j < 18; ++j) {
        int idx = t + j * 256;
        async_copy16((const char*)WtF + (size_t)idx * 16, (char*)Bs + idx * 16);
    }

    // per-lane spiral indices for the 4 m-subtiles, vectorized 4+4+1
    int src[4][S_];
    #pragma unroll
    for (int mi = 0; mi < 4; ++mi) {
        int m = mbase + mi * 16 + l16;
        int mc = (m < N_OUT_) ? m : 0;
        const int* sp = spiral + (size_t)mc * S_;
        int4 a0 = *reinterpret_cast<const int4*>(sp);
        int4 a1 = *reinterpret_cast<const int4*>(sp + 4);
        src[mi][0] = a0.x; src[mi][1] = a0.y; src[mi][2] = a0.z; src[mi][3] = a0.w;
        src[mi][4] = a1.x; src[mi][5] = a1.y; src[mi][6] = a1.z; src[mi][7] = a1.w;
        src[mi][8] = sp[8];
    }
    const __bf16* poolb = pooled + (size_t)b * N_OUT_ * C_;

    __syncthreads();   // staging drained (single barrier of the kernel)

    floatx4 acc[4][4] = {};
    bf16x8 A0[4][2], A1[4][2], A2[4][2], A3[4][2];

    auto loadA = [&](int s, bf16x8 (*A)[2]) {
        #pragma unroll
        for (int mi = 0; mi < 4; ++mi) {
            const __bf16* p = poolb + (size_t)src[mi][s] * C_ + quad * 8;
            A[mi][0] = *reinterpret_cast<const bf16x8*>(p);
            A[mi][1] = *reinterpret_cast<const bf16x8*>(p + 32);
        }
    };
    auto bufFor = [&](int s) -> bf16x8 (*)[2] {
        switch (s & 3) {
            case 0:  return A0;
            case 1:  return A1;
            case 2:  return A2;
            default: return A3;
        }
    };

    loadA(0, A0);
    loadA(1, A1);
    loadA(2, A2);
    #pragma unroll
    for (int s = 0; s < S_; ++s) {
        if (s + 3 < S_) {
            loadA(s + 3, bufFor(s + 3));           // depth-3 prefetch
            __builtin_amdgcn_sched_barrier(0);     // pin: loads stay ahead of MFMAs
        }
        bf16x8 (*A)[2] = bufFor(s);
        #pragma unroll
        for (int kc = 0; kc < 2; ++kc) {
            #pragma unroll
            for (int nt = 0; nt < 4; ++nt) {
                int kb = s * 8 + kc * 4 + quad;
                bf16x8 bb = *reinterpret_cast<const bf16x8*>(
                    Bs + (((kb << 6) + (nt << 4) + l16) << 3));
                #pragma unroll
                for (int mi = 0; mi < 4; ++mi)
                    acc[mi][nt] = __builtin_amdgcn_mfma_f32_16x16x32_bf16(
                        A[mi][kc], bb, acc[mi][nt], 0, 0, 0);
            }
        }
    }

    // epilogue: D[m = quad*4 + i][n = l16] per (mi, nt) tile, nontemporal
    float* outb = out + (size_t)b * N_OUT_ * C_;
    #pragma unroll
    for (int mi = 0; mi < 4; ++mi) {
        #pragma unroll
        for (int nt = 0; nt < 4; ++nt) {
            float bn = bias[nt * 16 + l16];
            #pragma unroll
            for (int i = 0; i < 4; ++i) {
                int mm = mbase + mi * 16 + quad * 4 + i;
                if (mm < N_OUT_) {
                    float v = acc[mi][nt][i] + bn;
                    v = (v > 0.0f) ? v : expm1f(v);
                    __builtin_nontemporal_store(v, &outb[(size_t)mm * C_ + nt * 16 + l16]);
                }
            }
        }
    }
}

extern "C" void kernel_launch(void* const* d_in, const int* in_sizes, int n_in,
                              void* d_out, int out_size, void* d_ws, size_t ws_size,
                              hipStream_t stream) {
    const float* x      = (const float*)d_in[0];
    const float* tvals  = (const float*)d_in[1];
    const int*   trow   = (const int*)d_in[2];
    const int*   tcol   = (const int*)d_in[3];
    const int*   spiral = (const int*)d_in[4];
    const float* W      = (const float*)d_in[5];
    const float* bias   = (const float*)d_in[6];
    float* out = (float*)d_out;

    char* ws = (char*)d_ws;
    size_t off = 0;
    auto alloc = [&](size_t bytes) -> void* {
        void* p = ws + off;
        off += (bytes + 255) & ~(size_t)255;
        return p;
    };
    __bf16* pooled  = (__bf16*)alloc((size_t)B_ * N_OUT_ * C_ * 2);   // 51.2 MB
    __bf16* WtF     = (__bf16*)alloc(72 * 64 * 8 * 2);
    int*    cursor  = (int*)alloc(N_OUT_ * 4);
    int*    offsets = (int*)alloc((N_OUT_ + 1) * 4);
    int*    ecol    = (int*)alloc(NNZ_ * 4);
    float*  eval    = (float*)alloc(NNZ_ * 4);
    int*    counts  = (int*)alloc(N_OUT_ * 4);

    init_kernel<<<(72 * 64 * 8 + 255) / 256, 256, 0, stream>>>(W, WtF, counts);
    hist_kernel<<<(NNZ_ + 255) / 256, 256, 0, stream>>>(trow, counts, NNZ_);
    scan_kernel<<<1, 1024, 0, stream>>>(counts, offsets, cursor, N_OUT_);
    fill_kernel<<<(NNZ_ + 255) / 256, 256, 0, stream>>>(trow, tcol, tvals, cursor, ecol, eval, NNZ_);
    pool_kernel<<<8 * (N_OUT_ / 2), 256, 0, stream>>>(x, offsets, ecol, eval, pooled);
    gemm_kernel<<<8 * (2 * MT2_), 256, 0, stream>>>(pooled, spiral, WtF, bias, out);
}

// Round 10
// 315.936 us; speedup vs baseline: 2.3662x; 1.1956x over previous
//
#include <hip/hip_runtime.h>

#define B_     16
#define N_IN_  6250
#define N_OUT_ 25000
#define C_     64
#define S_     9
#define NNZ_   75000
#define MT_A   49           // gemm_a: 49 tiles of 256 rows -> m in [0, 12544)
#define MB_OFF 12544        // gemm_b m-range start
#define GM_    32           // gemm_b rows per block
#define NBLK_B 390          // ceil((25000-12544)/32)

typedef __bf16 bf16x8 __attribute__((ext_vector_type(8)));
typedef float floatx4 __attribute__((ext_vector_type(4)));

__device__ inline void async_copy16(const void* g, void* l) {
    __builtin_amdgcn_global_load_lds(
        (const __attribute__((address_space(1))) void*)g,
        (__attribute__((address_space(3))) void*)l, 16, 0, 0);
}

// ---------------- init: zero counts + W -> WtF (one node) ----------------
__global__ void init_kernel(const float* __restrict__ W, __bf16* __restrict__ WtF,
                            int* __restrict__ counts) {
    int i = blockIdx.x * blockDim.x + threadIdx.x;
    if (i < N_OUT_) counts[i] = 0;
    if (i < 72 * 64 * 8) {
        int kb = i >> 9;
        int n  = (i >> 3) & 63;
        int j  = i & 7;
        WtF[i] = (__bf16)W[(kb * 8 + j) * 64 + n];
    }
}

// ---------------- CSR build ----------------

__global__ void hist_kernel(const int* __restrict__ rows, int* __restrict__ counts, int nnz) {
    int i = blockIdx.x * blockDim.x + threadIdx.x;
    if (i < nnz) atomicAdd(&counts[rows[i]], 1);
}

__global__ __launch_bounds__(1024) void scan_kernel(
        const int* __restrict__ counts, int* __restrict__ offsets,
        int* __restrict__ cursor, int n) {
    __shared__ int wsum[16];
    __shared__ int carry;
    int t = threadIdx.x;
    int wid = t >> 6, lane = t & 63;
    if (t == 0) carry = 0;
    __syncthreads();
    for (int base = 0; base < n; base += 1024) {
        int i = base + t;
        int v = (i < n) ? counts[i] : 0;
        int s = v;
        #pragma unroll
        for (int d = 1; d < 64; d <<= 1) {
            int u = __shfl_up(s, d, 64);
            if (lane >= d) s += u;
        }
        if (lane == 63) wsum[wid] = s;
        __syncthreads();
        if (wid == 0 && lane < 16) {
            int ws = wsum[lane];
            #pragma unroll
            for (int d = 1; d < 16; d <<= 1) {
                int u = __shfl_up(ws, d, 64);
                if (lane >= d) ws += u;
            }
            wsum[lane] = ws;
        }
        __syncthreads();
        int wave_off = (wid == 0) ? 0 : wsum[wid - 1];
        int incl = s + wave_off + carry;
        if (i < n) {
            int o = incl - v;
            offsets[i] = o;
            cursor[i] = o;
        }
        __syncthreads();
        if (t == 1023) carry = incl;
        __syncthreads();
    }
    if (t == 0) offsets[n] = carry;
}

__global__ void fill_kernel(const int* __restrict__ rows, const int* __restrict__ cols,
                            const float* __restrict__ vals, int* __restrict__ cursor,
                            int* __restrict__ ecol, float* __restrict__ eval, int nnz) {
    int i = blockIdx.x * blockDim.x + threadIdx.x;
    if (i < nnz) {
        int p = atomicAdd(&cursor[rows[i]], 1);
        ecol[p] = cols[i];
        eval[p] = vals[i];
    }
}

// ---------------- pooling (round-2 proven), dual-layout store ----------------
// Writes pooled[b][n][c] (for gemm_a) AND pooledT[n][b][c] (for gemm_b).
__global__ __launch_bounds__(256) void pool_kernel(
        const float* __restrict__ x, const int* __restrict__ offsets,
        const int* __restrict__ ecol, const float* __restrict__ eval,
        __bf16* __restrict__ pooled, __bf16* __restrict__ pooledT) {
    int t = threadIdx.x;
    int wid = t >> 6, lane = t & 63;
    int row = blockIdx.x * 4 + wid;
    int b = lane >> 2;
    int cq = (lane & 3) << 4;
    int beg = offsets[row], end = offsets[row + 1];

    const float* xb = x + (size_t)b * N_IN_ * C_ + cq;
    floatx4 acc[4] = {};

    int col = 0; float v = 0.f;
    if (beg < end) { col = ecol[beg]; v = eval[beg]; }
    for (int k = beg; k < end; ++k) {
        int col2 = 0; float v2 = 0.f;
        if (k + 1 < end) { col2 = ecol[k + 1]; v2 = eval[k + 1]; }
        const floatx4* xp = reinterpret_cast<const floatx4*>(xb + (size_t)col * C_);
        #pragma unroll
        for (int j = 0; j < 4; ++j) acc[j] += xp[j] * v;
        col = col2; v = v2;
    }

    bf16x8 o0, o1;
    #pragma unroll
    for (int j = 0; j < 4; ++j) {
        o0[j]     = (__bf16)acc[0][j];
        o0[j + 4] = (__bf16)acc[1][j];
        o1[j]     = (__bf16)acc[2][j];
        o1[j + 4] = (__bf16)acc[3][j];
    }
    __bf16* op = pooled + ((size_t)b * N_OUT_ + row) * C_ + cq;
    *reinterpret_cast<bf16x8*>(op)     = o0;
    *reinterpret_cast<bf16x8*>(op + 8) = o1;
    __bf16* opT = pooledT + ((size_t)row * 16 + b) * C_ + cq;
    *reinterpret_cast<bf16x8*>(opT)     = o0;
    *reinterpret_cast<bf16x8*>(opT + 8) = o1;
}

// ---------------- gemm_a: round-6 structure, m in [0, 12544) ----------------
// Scattered per-lane A-gathers (16x64B segments/instr), XCD-affine batches,
// nontemporal out-stores. The L2-request-rate-bound reference arm.
__global__ __launch_bounds__(256, 2) void gemm_a_kernel(
        const __bf16* __restrict__ pooled, const int* __restrict__ spiral,
        const __bf16* __restrict__ WtF, const float* __restrict__ bias,
        float* __restrict__ out) {
    __shared__ __bf16 Bs[72 * 64 * 8];

    int bx = blockIdx.x;
    int xcd = bx & 7;
    int rr = bx >> 3;                    // 0..2*MT_A-1
    int half = (rr >= MT_A) ? 1 : 0;
    int mt = rr - half * MT_A;           // 0..48
    int b = xcd + 8 * half;

    int t = threadIdx.x;
    int wave = t >> 6, lane = t & 63;
    int quad = lane >> 4, l16 = lane & 15;
    int mbase = mt * 256 + wave * 64;

    #pragma unroll
    for (int j = 0; j < 18; ++j) {
        int idx = t + j * 256;
        async_copy16((const char*)WtF + (size_t)idx * 16, (char*)Bs + idx * 16);
    }

    int src[4][S_];
    #pragma unroll
    for (int mi = 0; mi < 4; ++mi) {
        int m = mbase + mi * 16 + l16;
        const int* sp = spiral + (size_t)m * S_;
        int4 a0 = *reinterpret_cast<const int4*>(sp);
        int4 a1 = *reinterpret_cast<const int4*>(sp + 4);
        src[mi][0] = a0.x; src[mi][1] = a0.y; src[mi][2] = a0.z; src[mi][3] = a0.w;
        src[mi][4] = a1.x; src[mi][5] = a1.y; src[mi][6] = a1.z; src[mi][7] = a1.w;
        src[mi][8] = sp[8];
    }
    const __bf16* poolb = pooled + (size_t)b * N_OUT_ * C_;

    __syncthreads();

    floatx4 acc[4][4] = {};
    bf16x8 A0[4][2], A1[4][2], A2[4][2], A3[4][2];

    auto loadA = [&](int s, bf16x8 (*A)[2]) {
        #pragma unroll
        for (int mi = 0; mi < 4; ++mi) {
            const __bf16* p = poolb + (size_t)src[mi][s] * C_ + quad * 8;
            A[mi][0] = *reinterpret_cast<const bf16x8*>(p);
            A[mi][1] = *reinterpret_cast<const bf16x8*>(p + 32);
        }
    };
    auto bufFor = [&](int s) -> bf16x8 (*)[2] {
        switch (s & 3) {
            case 0:  return A0;
            case 1:  return A1;
            case 2:  return A2;
            default: return A3;
        }
    };

    loadA(0, A0);
    loadA(1, A1);
    loadA(2, A2);
    #pragma unroll
    for (int s = 0; s < S_; ++s) {
        if (s + 3 < S_) {
            loadA(s + 3, bufFor(s + 3));
            __builtin_amdgcn_sched_barrier(0);
        }
        bf16x8 (*A)[2] = bufFor(s);
        #pragma unroll
        for (int kc = 0; kc < 2; ++kc) {
            #pragma unroll
            for (int nt = 0; nt < 4; ++nt) {
                int kb = s * 8 + kc * 4 + quad;
                bf16x8 bb = *reinterpret_cast<const bf16x8*>(
                    Bs + (((kb << 6) + (nt << 4) + l16) << 3));
                #pragma unroll
                for (int mi = 0; mi < 4; ++mi)
                    acc[mi][nt] = __builtin_amdgcn_mfma_f32_16x16x32_bf16(
                        A[mi][kc], bb, acc[mi][nt], 0, 0, 0);
            }
        }
    }

    float* outb = out + (size_t)b * N_OUT_ * C_;
    #pragma unroll
    for (int mi = 0; mi < 4; ++mi) {
        #pragma unroll
        for (int nt = 0; nt < 4; ++nt) {
            float bn = bias[nt * 16 + l16];
            #pragma unroll
            for (int i = 0; i < 4; ++i) {
                int mm = mbase + mi * 16 + quad * 4 + i;
                float v = acc[mi][nt][i] + bn;
                v = (v > 0.0f) ? v : expm1f(v);
                __builtin_nontemporal_store(v, &outb[(size_t)mm * C_ + nt * 16 + l16]);
            }
        }
    }
}

// ---------------- gemm_b: round-7 coalesced staging + NT stores, m in [12544, 25000)
// Block = 512 thr, 32 m-rows x 16 batches; per step stage 32 gathered 2KB
// pooledT rows (contiguous global_load_lds) + W slice, double-buffered.
// NEW vs round 7: nontemporal epilogue -> out stream doesn't evict pooledT
// from L3 (round-6 evidence: NT cut FETCH 66->43MB).
__global__ __launch_bounds__(512, 2) void gemm_b_kernel(
        const __bf16* __restrict__ pooledT, const int* __restrict__ spiral,
        const __bf16* __restrict__ WtF, const float* __restrict__ bias,
        float* __restrict__ out) {
    __shared__ __bf16 As[2][GM_ * 1024];   // 2 x 64KB
    __shared__ __bf16 Ws[2][4096];         // 2 x 8KB
    __shared__ int spp[GM_][12];

    int bx = blockIdx.x;
    int mbase = MB_OFF + bx * GM_;
    int t = threadIdx.x;
    int wave = t >> 6, lane = t & 63;
    int q = lane >> 4, l16 = lane & 15;

    if (t < GM_ * S_) {
        int r = t / S_, s = t - r * S_;
        int m = mbase + r;
        int mc = (m < N_OUT_) ? m : (N_OUT_ - 1);
        spp[r][s] = spiral[mc * S_ + s];
    }
    __syncthreads();

    auto stage = [&](int s, int d) {
        #pragma unroll
        for (int k = 0; k < 8; ++k) {
            int c = t + k * 512;
            int r = c >> 7;
            int f = c & 127;
            async_copy16((const char*)pooledT + (size_t)spp[r][s] * 2048
                             + ((f ^ (r & 15)) << 4),
                         (char*)&As[d][0] + ((size_t)c << 4));
        }
        async_copy16((const char*)WtF + (size_t)s * 8192 + ((size_t)t << 4),
                     (char*)&Ws[d][0] + ((size_t)t << 4));
    };

    stage(0, 0);
    __syncthreads();

    floatx4 acc[2][2][4] = {};

    #pragma unroll
    for (int s = 0; s < S_; ++s) {
        int cur = s & 1;
        if (s + 1 < S_) stage(s + 1, cur ^ 1);

        bf16x8 wf[4][2];
        #pragma unroll
        for (int kc = 0; kc < 2; ++kc)
            #pragma unroll
            for (int nt = 0; nt < 4; ++nt)
                wf[nt][kc] = *reinterpret_cast<const bf16x8*>(
                    &Ws[cur][(((kc << 2) + q) << 6 | (nt << 4) | l16) << 3]);

        bf16x8 af[2][2][2];
        #pragma unroll
        for (int bb = 0; bb < 2; ++bb) {
            int bg = 2 * wave + bb;
            #pragma unroll
            for (int mi = 0; mi < 2; ++mi) {
                int r = mi * 16 + l16;
                #pragma unroll
                for (int kc = 0; kc < 2; ++kc) {
                    int F = (bg << 3) + (kc << 2) + q;
                    af[bb][mi][kc] = *reinterpret_cast<const bf16x8*>(
                        &As[cur][(size_t)r * 1024 + ((F ^ l16) << 3)]);
                }
            }
        }

        #pragma unroll
        for (int kc = 0; kc < 2; ++kc)
            #pragma unroll
            for (int nt = 0; nt < 4; ++nt)
                #pragma unroll
                for (int bb = 0; bb < 2; ++bb)
                    #pragma unroll
                    for (int mi = 0; mi < 2; ++mi)
                        acc[bb][mi][nt] = __builtin_amdgcn_mfma_f32_16x16x32_bf16(
                            af[bb][mi][kc], wf[nt][kc], acc[bb][mi][nt], 0, 0, 0);

        __syncthreads();
    }

    #pragma unroll
    for (int bb = 0; bb < 2; ++bb) {
        int bg = 2 * wave + bb;
        float* outb = out + (size_t)bg * N_OUT_ * C_;
        #pragma unroll
        for (int mi = 0; mi < 2; ++mi) {
            #pragma unroll
            for (int nt = 0; nt < 4; ++nt) {
                int col = (nt << 4) + l16;
                float bn = bias[col];
                #pragma unroll
                for (int i = 0; i < 4; ++i) {
                    int mm = mbase + mi * 16 + q * 4 + i;
                    if (mm < N_OUT_) {
                        float v = acc[bb][mi][nt][i] + bn;
                        v = (v > 0.0f) ? v : expm1f(v);
                        __builtin_nontemporal_store(v, &outb[(size_t)mm * C_ + col]);
                    }
                }
            }
        }
    }
}

extern "C" void kernel_launch(void* const* d_in, const int* in_sizes, int n_in,
                              void* d_out, int out_size, void* d_ws, size_t ws_size,
                              hipStream_t stream) {
    const float* x      = (const float*)d_in[0];
    const float* tvals  = (const float*)d_in[1];
    const int*   trow   = (const int*)d_in[2];
    const int*   tcol   = (const int*)d_in[3];
    const int*   spiral = (const int*)d_in[4];
    const float* W      = (const float*)d_in[5];
    const float* bias   = (const float*)d_in[6];
    float* out = (float*)d_out;

    char* ws = (char*)d_ws;
    size_t off = 0;
    auto alloc = [&](size_t bytes) -> void* {
        void* p = ws + off;
        off += (bytes + 255) & ~(size_t)255;
        return p;
    };
    __bf16* pooled  = (__bf16*)alloc((size_t)B_ * N_OUT_ * C_ * 2);   // 51.2 MB
    __bf16* pooledT = (__bf16*)alloc((size_t)N_OUT_ * 16 * C_ * 2);   // 51.2 MB
    __bf16* WtF     = (__bf16*)alloc(72 * 64 * 8 * 2);
    int*    cursor  = (int*)alloc(N_OUT_ * 4);
    int*    offsets = (int*)alloc((N_OUT_ + 1) * 4);
    int*    ecol    = (int*)alloc(NNZ_ * 4);
    float*  eval    = (float*)alloc(NNZ_ * 4);
    int*    counts  = (int*)alloc(N_OUT_ * 4);

    init_kernel<<<(72 * 64 * 8 + 255) / 256, 256, 0, stream>>>(W, WtF, counts);
    hist_kernel<<<(NNZ_ + 255) / 256, 256, 0, stream>>>(trow, counts, NNZ_);
    scan_kernel<<<1, 1024, 0, stream>>>(counts, offsets, cursor, N_OUT_);
    fill_kernel<<<(NNZ_ + 255) / 256, 256, 0, stream>>>(trow, tcol, tvals, cursor, ecol, eval, NNZ_);
    pool_kernel<<<N_OUT_ / 4, 256, 0, stream>>>(x, offsets, ecol, eval, pooled, pooledT);
    gemm_a_kernel<<<8 * (2 * MT_A), 256, 0, stream>>>(pooled, spiral, WtF, bias, out);
    gemm_b_kernel<<<NBLK_B, 512, 0, stream>>>(pooledT, spiral, WtF, bias, out);
}

// Round 11
// 305.679 us; speedup vs baseline: 2.4456x; 1.0336x over previous
//
#include <hip/hip_runtime.h>

#define B_     16
#define N_IN_  6250
#define N_OUT_ 25000
#define C_     64
#define S_     9
#define NNZ_   75000
#define MT2_   98           // ceil(N_OUT/256)

typedef __bf16 bf16x8 __attribute__((ext_vector_type(8)));
typedef float floatx4 __attribute__((ext_vector_type(4)));

__device__ inline void async_copy16(const void* g, void* l) {
    __builtin_amdgcn_global_load_lds(
        (const __attribute__((address_space(1))) void*)g,
        (__attribute__((address_space(3))) void*)l, 16, 0, 0);
}

// ---------------- init: zero counts + W -> WtF (one node) ----------------
// WtF[(kb*64 + n)*8 + j] = W[(kb*8 + j)*64 + n], kb = k/8 in [0,72).
__global__ void init_kernel(const float* __restrict__ W, __bf16* __restrict__ WtF,
                            int* __restrict__ counts) {
    int i = blockIdx.x * blockDim.x + threadIdx.x;
    if (i < N_OUT_) counts[i] = 0;
    if (i < 72 * 64 * 8) {
        int kb = i >> 9;
        int n  = (i >> 3) & 63;
        int j  = i & 7;
        WtF[i] = (__bf16)W[(kb * 8 + j) * 64 + n];
    }
}

// ---------------- CSR build ----------------

__global__ void hist_kernel(const int* __restrict__ rows, int* __restrict__ counts, int nnz) {
    int i = blockIdx.x * blockDim.x + threadIdx.x;
    if (i < nnz) atomicAdd(&counts[rows[i]], 1);
}

// single-block scan over counts -> offsets (+cursor copy); proven R3/R9/R10
__global__ __launch_bounds__(1024) void scan_kernel(
        const int* __restrict__ counts, int* __restrict__ offsets,
        int* __restrict__ cursor, int n) {
    __shared__ int wsum[16];
    __shared__ int carry;
    int t = threadIdx.x;
    int wid = t >> 6, lane = t & 63;
    if (t == 0) carry = 0;
    __syncthreads();
    for (int base = 0; base < n; base += 1024) {
        int i = base + t;
        int v = (i < n) ? counts[i] : 0;
        int s = v;
        #pragma unroll
        for (int d = 1; d < 64; d <<= 1) {
            int u = __shfl_up(s, d, 64);
            if (lane >= d) s += u;
        }
        if (lane == 63) wsum[wid] = s;
        __syncthreads();
        if (wid == 0 && lane < 16) {
            int ws = wsum[lane];
            #pragma unroll
            for (int d = 1; d < 16; d <<= 1) {
                int u = __shfl_up(ws, d, 64);
                if (lane >= d) ws += u;
            }
            wsum[lane] = ws;
        }
        __syncthreads();
        int wave_off = (wid == 0) ? 0 : wsum[wid - 1];
        int incl = s + wave_off + carry;
        if (i < n) {
            int o = incl - v;
            offsets[i] = o;
            cursor[i] = o;
        }
        __syncthreads();
        if (t == 1023) carry = incl;
        __syncthreads();
    }
    if (t == 0) offsets[n] = carry;
}

__global__ void fill_kernel(const int* __restrict__ rows, const int* __restrict__ cols,
                            const float* __restrict__ vals, int* __restrict__ cursor,
                            int* __restrict__ ecol, float* __restrict__ eval, int nnz) {
    int i = blockIdx.x * blockDim.x + threadIdx.x;
    if (i < nnz) {
        int p = atomicAdd(&cursor[rows[i]], 1);
        ecol[p] = cols[i];
        eval[p] = vals[i];
    }
}

// ---------------- pooling (CSR gather), wave-per-row (R2 proven) ------------
// grid: N_OUT/4 blocks x 256 threads = 4 waves; wave w owns row blockIdx*4+w.
// Lane = (batch b = lane>>2, channel quad cq = (lane&3)*16). 16 f32 acc/lane.
__global__ __launch_bounds__(256) void pool_kernel(
        const float* __restrict__ x, const int* __restrict__ offsets,
        const int* __restrict__ ecol, const float* __restrict__ eval,
        __bf16* __restrict__ pooled) {
    int t = threadIdx.x;
    int wid = t >> 6, lane = t & 63;
    int row = blockIdx.x * 4 + wid;
    int b = lane >> 2;
    int cq = (lane & 3) << 4;
    int beg = offsets[row], end = offsets[row + 1];

    const float* xb = x + (size_t)b * N_IN_ * C_ + cq;
    floatx4 acc[4] = {};

    int col = 0; float v = 0.f;
    if (beg < end) { col = ecol[beg]; v = eval[beg]; }
    for (int k = beg; k < end; ++k) {
        int col2 = 0; float v2 = 0.f;
        if (k + 1 < end) { col2 = ecol[k + 1]; v2 = eval[k + 1]; }
        const floatx4* xp = reinterpret_cast<const floatx4*>(xb + (size_t)col * C_);
        #pragma unroll
        for (int j = 0; j < 4; ++j) acc[j] += xp[j] * v;
        col = col2; v = v2;
    }

    __bf16* op = pooled + ((size_t)b * N_OUT_ + row) * C_ + cq;
    bf16x8 o0, o1;
    #pragma unroll
    for (int j = 0; j < 4; ++j) {
        o0[j]     = (__bf16)acc[0][j];
        o0[j + 4] = (__bf16)acc[1][j];
        o1[j]     = (__bf16)acc[2][j];
        o1[j + 4] = (__bf16)acc[3][j];
    }
    *reinterpret_cast<bf16x8*>(op)     = o0;
    *reinterpret_cast<bf16x8*>(op + 8) = o1;
}

// ---------------- spiral gather + GEMM + bias + ELU -------------------------
// Round-6 structure UNPINNED: no sched_barrier(0) in the K-loop (m141 lesson:
// order-pinning defeats the compiler's software pipelining and forces
// near-drain waitcnts each step — consistent with depth-1/2/3 prefetch all
// measuring identical). Depth-3 rotating buffers give the scheduler 24
// independent gathers to pipeline with counted vmcnt. Plain stores (R2's
// clean 102MB write profile). XCD-affine batches for L2 residency of pooled.
__global__ __launch_bounds__(256, 2) void gemm_kernel(
        const __bf16* __restrict__ pooled, const int* __restrict__ spiral,
        const __bf16* __restrict__ WtF, const float* __restrict__ bias,
        float* __restrict__ out) {
    __shared__ __bf16 Bs[72 * 64 * 8];   // 73728 B -> 2 blocks/CU

    int bx = blockIdx.x;
    int xcd = bx & 7;
    int rr = bx >> 3;                    // 0..2*MT2_-1
    int half = (rr >= MT2_) ? 1 : 0;
    int mt = rr - half * MT2_;           // 0..97
    int b = xcd + 8 * half;

    int t = threadIdx.x;
    int wave = t >> 6, lane = t & 63;
    int quad = lane >> 4, l16 = lane & 15;
    int mbase = mt * 256 + wave * 64;

    // stage WtF -> Bs, lane-linear 16B chunks (4608 total, 18/thread)
    #pragma unroll
    for (int j = 0; j < 18; ++j) {
        int idx = t + j * 256;
        async_copy16((const char*)WtF + (size_t)idx * 16, (char*)Bs + idx * 16);
    }

    // per-lane spiral indices for the 4 m-subtiles, vectorized 4+4+1
    int src[4][S_];
    #pragma unroll
    for (int mi = 0; mi < 4; ++mi) {
        int m = mbase + mi * 16 + l16;
        int mc = (m < N_OUT_) ? m : 0;
        const int* sp = spiral + (size_t)mc * S_;
        int4 a0 = *reinterpret_cast<const int4*>(sp);
        int4 a1 = *reinterpret_cast<const int4*>(sp + 4);
        src[mi][0] = a0.x; src[mi][1] = a0.y; src[mi][2] = a0.z; src[mi][3] = a0.w;
        src[mi][4] = a1.x; src[mi][5] = a1.y; src[mi][6] = a1.z; src[mi][7] = a1.w;
        src[mi][8] = sp[8];
    }
    const __bf16* poolb = pooled + (size_t)b * N_OUT_ * C_;

    __syncthreads();   // staging drained (single barrier of the kernel)

    floatx4 acc[4][4] = {};
    bf16x8 A0[4][2], A1[4][2], A2[4][2], A3[4][2];

    auto loadA = [&](int s, bf16x8 (*A)[2]) {
        #pragma unroll
        for (int mi = 0; mi < 4; ++mi) {
            const __bf16* p = poolb + (size_t)src[mi][s] * C_ + quad * 8;
            A[mi][0] = *reinterpret_cast<const bf16x8*>(p);
            A[mi][1] = *reinterpret_cast<const bf16x8*>(p + 32);
        }
    };
    auto bufFor = [&](int s) -> bf16x8 (*)[2] {
        switch (s & 3) {
            case 0:  return A0;
            case 1:  return A1;
            case 2:  return A2;
            default: return A3;
        }
    };

    loadA(0, A0);
    loadA(1, A1);
    loadA(2, A2);
    #pragma unroll
    for (int s = 0; s < S_; ++s) {
        if (s + 3 < S_) {
            loadA(s + 3, bufFor(s + 3));   // depth-3 prefetch, UNPINNED
        }
        bf16x8 (*A)[2] = bufFor(s);
        #pragma unroll
        for (int kc = 0; kc < 2; ++kc) {
            #pragma unroll
            for (int nt = 0; nt < 4; ++nt) {
                int kb = s * 8 + kc * 4 + quad;
                bf16x8 bb = *reinterpret_cast<const bf16x8*>(
                    Bs + (((kb << 6) + (nt << 4) + l16) << 3));
                #pragma unroll
                for (int mi = 0; mi < 4; ++mi)
                    acc[mi][nt] = __builtin_amdgcn_mfma_f32_16x16x32_bf16(
                        A[mi][kc], bb, acc[mi][nt], 0, 0, 0);
            }
        }
    }

    // epilogue: D[m = quad*4 + i][n = l16] per (mi, nt) tile
    float* outb = out + (size_t)b * N_OUT_ * C_;
    #pragma unroll
    for (int mi = 0; mi < 4; ++mi) {
        #pragma unroll
        for (int nt = 0; nt < 4; ++nt) {
            float bn = bias[nt * 16 + l16];
            #pragma unroll
            for (int i = 0; i < 4; ++i) {
                int mm = mbase + mi * 16 + quad * 4 + i;
                if (mm < N_OUT_) {
                    float v = acc[mi][nt][i] + bn;
                    v = (v > 0.0f) ? v : expm1f(v);
                    outb[(size_t)mm * C_ + nt * 16 + l16] = v;
                }
            }
        }
    }
}

extern "C" void kernel_launch(void* const* d_in, const int* in_sizes, int n_in,
                              void* d_out, int out_size, void* d_ws, size_t ws_size,
                              hipStream_t stream) {
    const float* x      = (const float*)d_in[0];
    const float* tvals  = (const float*)d_in[1];
    const int*   trow   = (const int*)d_in[2];
    const int*   tcol   = (const int*)d_in[3];
    const int*   spiral = (const int*)d_in[4];
    const float* W      = (const float*)d_in[5];
    const float* bias   = (const float*)d_in[6];
    float* out = (float*)d_out;

    char* ws = (char*)d_ws;
    size_t off = 0;
    auto alloc = [&](size_t bytes) -> void* {
        void* p = ws + off;
        off += (bytes + 255) & ~(size_t)255;
        return p;
    };
    __bf16* pooled  = (__bf16*)alloc((size_t)B_ * N_OUT_ * C_ * 2);   // 51.2 MB
    __bf16* WtF     = (__bf16*)alloc(72 * 64 * 8 * 2);
    int*    cursor  = (int*)alloc(N_OUT_ * 4);
    int*    offsets = (int*)alloc((N_OUT_ + 1) * 4);
    int*    ecol    = (int*)alloc(NNZ_ * 4);
    float*  eval    = (float*)alloc(NNZ_ * 4);
    int*    counts  = (int*)alloc(N_OUT_ * 4);

    init_kernel<<<(72 * 64 * 8 + 255) / 256, 256, 0, stream>>>(W, WtF, counts);
    hist_kernel<<<(NNZ_ + 255) / 256, 256, 0, stream>>>(trow, counts, NNZ_);
    scan_kernel<<<1, 1024, 0, stream>>>(counts, offsets, cursor, N_OUT_);
    fill_kernel<<<(NNZ_ + 255) / 256, 256, 0, stream>>>(trow, tcol, tvals, cursor, ecol, eval, NNZ_);
    pool_kernel<<<N_OUT_ / 4, 256, 0, stream>>>(x, offsets, ecol, eval, pooled);
    gemm_kernel<<<8 * (2 * MT2_), 256, 0, stream>>>(pooled, spiral, WtF, bias, out);
}

// Round 12
// 291.925 us; speedup vs baseline: 2.5609x; 1.0471x over previous
//
#include <hip/hip_runtime.h>

#define B_     16
#define N_IN_  6250
#define N_OUT_ 25000
#define C_     64
#define S_     9
#define NNZ_   75000
#define MT2_   98           // ceil(N_OUT/256)

typedef __bf16 bf16x8 __attribute__((ext_vector_type(8)));
typedef __bf16 bf16x4 __attribute__((ext_vector_type(4)));
typedef float floatx4 __attribute__((ext_vector_type(4)));

__device__ inline void async_copy16(const void* g, void* l) {
    __builtin_amdgcn_global_load_lds(
        (const __attribute__((address_space(1))) void*)g,
        (__attribute__((address_space(3))) void*)l, 16, 0, 0);
}

// ---------------- init: zero counts + W -> WtF (one node) ----------------
// WtF[(kb*64 + n)*8 + j] = W[(kb*8 + j)*64 + n], kb = k/8 in [0,72).
__global__ void init_kernel(const float* __restrict__ W, __bf16* __restrict__ WtF,
                            int* __restrict__ counts) {
    int i = blockIdx.x * blockDim.x + threadIdx.x;
    if (i < N_OUT_) counts[i] = 0;
    if (i < 72 * 64 * 8) {
        int kb = i >> 9;
        int n  = (i >> 3) & 63;
        int j  = i & 7;
        WtF[i] = (__bf16)W[(kb * 8 + j) * 64 + n];
    }
}

// ---------------- CSR build (R2-proven chain) ----------------

__global__ void hist_kernel(const int* __restrict__ rows, int* __restrict__ counts, int nnz) {
    int i = blockIdx.x * blockDim.x + threadIdx.x;
    if (i < nnz) atomicAdd(&counts[rows[i]], 1);
}

__global__ void scan1_kernel(const int* __restrict__ counts, int* __restrict__ offsets,
                             int* __restrict__ bsum, int n) {
    __shared__ int wsum[16];
    int t = threadIdx.x;
    int wid = t >> 6, lane = t & 63;
    int i = blockIdx.x * 1024 + t;
    int v = (i < n) ? counts[i] : 0;
    int s = v;
    #pragma unroll
    for (int d = 1; d < 64; d <<= 1) {
        int u = __shfl_up(s, d, 64);
        if (lane >= d) s += u;
    }
    if (lane == 63) wsum[wid] = s;
    __syncthreads();
    if (wid == 0 && lane < 16) {
        int ws = wsum[lane];
        #pragma unroll
        for (int d = 1; d < 16; d <<= 1) {
            int u = __shfl_up(ws, d, 64);
            if (lane >= d) ws += u;
        }
        wsum[lane] = ws;
    }
    __syncthreads();
    int wave_off = (wid == 0) ? 0 : wsum[wid - 1];
    int incl = s + wave_off;
    if (i < n) offsets[i] = incl - v;
    if (t == 1023) bsum[blockIdx.x] = incl;
}

__global__ void scan2_kernel(int* __restrict__ bsum, int* __restrict__ offsets, int nblk, int n) {
    if (threadIdx.x == 0) {
        int t = 0;
        for (int i = 0; i < nblk; ++i) { int v = bsum[i]; bsum[i] = t; t += v; }
        offsets[n] = t;
    }
}

__global__ void scan3_kernel(int* __restrict__ offsets, const int* __restrict__ bsum,
                             int* __restrict__ cursor, int n) {
    int i = blockIdx.x * 1024 + threadIdx.x;
    if (i < n) {
        int o = offsets[i] + bsum[blockIdx.x];
        offsets[i] = o;
        cursor[i] = o;
    }
}

__global__ void fill_kernel(const int* __restrict__ rows, const int* __restrict__ cols,
                            const float* __restrict__ vals, int* __restrict__ cursor,
                            int* __restrict__ ecol, float* __restrict__ eval, int nnz) {
    int i = blockIdx.x * blockDim.x + threadIdx.x;
    if (i < nnz) {
        int p = atomicAdd(&cursor[rows[i]], 1);
        ecol[p] = cols[i];
        eval[p] = vals[i];
    }
}

// ---------------- pooling: XCD-affine, float4 lanes ----------------
// grid 8*3125: bx&7 = xcd -> batches {xcd, xcd+8}; per-XCD x slice = 3.2MB
// L2-RESIDENT (cuts gather latency ~600 -> ~200cyc; the MSHR wall scales
// inversely with latency). Wave = 2 rows x 2 batches x 16 lanes x float4
// (keeps R2's 16B/lane vector width — R4's regression was float2, not
// affinity). pooled[b] is written through the SAME XCD's L2 that gemm
// (b&7 mapping) later reads. Divergence between the two 32-lane row-halves
// costs ~max(count) — acceptable at avg 3 nnz/row.
__global__ __launch_bounds__(256) void pool_kernel(
        const float* __restrict__ x, const int* __restrict__ offsets,
        const int* __restrict__ ecol, const float* __restrict__ eval,
        __bf16* __restrict__ pooled) {
    int bx = blockIdx.x;
    int xcd = bx & 7;
    int rg = bx >> 3;                      // 0..3124 -> rows rg*8 .. rg*8+7
    int t = threadIdx.x;
    int wid = t >> 6, lane = t & 63;
    int r2  = lane >> 5;                   // which of the wave's 2 rows
    int b   = xcd + 8 * ((lane >> 4) & 1); // which of the XCD's 2 batches
    int l16 = lane & 15;                   // float4 slot within the row
    int row = rg * 8 + wid * 2 + r2;

    const float* xb = x + (size_t)b * N_IN_ * C_ + l16 * 4;
    int beg = offsets[row], end = offsets[row + 1];

    floatx4 acc = {};
    int col = 0; float v = 0.f;
    if (beg < end) { col = ecol[beg]; v = eval[beg]; }
    for (int k = beg; k < end; ++k) {
        int col2 = 0; float v2 = 0.f;
        if (k + 1 < end) { col2 = ecol[k + 1]; v2 = eval[k + 1]; }
        acc += *reinterpret_cast<const floatx4*>(xb + (size_t)col * C_) * v;
        col = col2; v = v2;
    }

    bf16x4 o;
    #pragma unroll
    for (int j = 0; j < 4; ++j) o[j] = (__bf16)acc[j];
    *reinterpret_cast<bf16x4*>(pooled + ((size_t)b * N_OUT_ + row) * C_ + l16 * 4) = o;
}

// ---------------- spiral gather + GEMM + bias + ELU -------------------------
// R11 structure (unpinned, depth-3 rotating A-prefetch) + NT out-stores (R6:
// cut FETCH 66->43MB by not thrashing L2 that serves the pooled gathers).
// XCD-affine: bx&7 = xcd, one batch per block, matching pool's mapping so
// pooled[b] is warm in the producing XCD's L2.
__global__ __launch_bounds__(256, 2) void gemm_kernel(
        const __bf16* __restrict__ pooled, const int* __restrict__ spiral,
        const __bf16* __restrict__ WtF, const float* __restrict__ bias,
        float* __restrict__ out) {
    __shared__ __bf16 Bs[72 * 64 * 8];   // 73728 B -> 2 blocks/CU

    int bx = blockIdx.x;
    int xcd = bx & 7;
    int rr = bx >> 3;                    // 0..2*MT2_-1
    int half = (rr >= MT2_) ? 1 : 0;
    int mt = rr - half * MT2_;           // 0..97
    int b = xcd + 8 * half;

    int t = threadIdx.x;
    int wave = t >> 6, lane = t & 63;
    int quad = lane >> 4, l16 = lane & 15;
    int mbase = mt * 256 + wave * 64;

    // stage WtF -> Bs, lane-linear 16B chunks (4608 total, 18/thread)
    #pragma unroll
    for (int j = 0; j < 18; ++j) {
        int idx = t + j * 256;
        async_copy16((const char*)WtF + (size_t)idx * 16, (char*)Bs + idx * 16);
    }

    // per-lane spiral indices for the 4 m-subtiles, vectorized 4+4+1
    int src[4][S_];
    #pragma unroll
    for (int mi = 0; mi < 4; ++mi) {
        int m = mbase + mi * 16 + l16;
        int mc = (m < N_OUT_) ? m : 0;
        const int* sp = spiral + (size_t)mc * S_;
        int4 a0 = *reinterpret_cast<const int4*>(sp);
        int4 a1 = *reinterpret_cast<const int4*>(sp + 4);
        src[mi][0] = a0.x; src[mi][1] = a0.y; src[mi][2] = a0.z; src[mi][3] = a0.w;
        src[mi][4] = a1.x; src[mi][5] = a1.y; src[mi][6] = a1.z; src[mi][7] = a1.w;
        src[mi][8] = sp[8];
    }
    const __bf16* poolb = pooled + (size_t)b * N_OUT_ * C_;

    __syncthreads();   // staging drained (single barrier of the kernel)

    floatx4 acc[4][4] = {};
    bf16x8 A0[4][2], A1[4][2], A2[4][2], A3[4][2];

    auto loadA = [&](int s, bf16x8 (*A)[2]) {
        #pragma unroll
        for (int mi = 0; mi < 4; ++mi) {
            const __bf16* p = poolb + (size_t)src[mi][s] * C_ + quad * 8;
            A[mi][0] = *reinterpret_cast<const bf16x8*>(p);
            A[mi][1] = *reinterpret_cast<const bf16x8*>(p + 32);
        }
    };
    auto bufFor = [&](int s) -> bf16x8 (*)[2] {
        switch (s & 3) {
            case 0:  return A0;
            case 1:  return A1;
            case 2:  return A2;
            default: return A3;
        }
    };

    loadA(0, A0);
    loadA(1, A1);
    loadA(2, A2);
    #pragma unroll
    for (int s = 0; s < S_; ++s) {
        if (s + 3 < S_) {
            loadA(s + 3, bufFor(s + 3));   // depth-3 prefetch, unpinned
        }
        bf16x8 (*A)[2] = bufFor(s);
        #pragma unroll
        for (int kc = 0; kc < 2; ++kc) {
            #pragma unroll
            for (int nt = 0; nt < 4; ++nt) {
                int kb = s * 8 + kc * 4 + quad;
                bf16x8 bb = *reinterpret_cast<const bf16x8*>(
                    Bs + (((kb << 6) + (nt << 4) + l16) << 3));
                #pragma unroll
                for (int mi = 0; mi < 4; ++mi)
                    acc[mi][nt] = __builtin_amdgcn_mfma_f32_16x16x32_bf16(
                        A[mi][kc], bb, acc[mi][nt], 0, 0, 0);
            }
        }
    }

    // epilogue: D[m = quad*4 + i][n = l16] per (mi, nt) tile, nontemporal
    float* outb = out + (size_t)b * N_OUT_ * C_;
    #pragma unroll
    for (int mi = 0; mi < 4; ++mi) {
        #pragma unroll
        for (int nt = 0; nt < 4; ++nt) {
            float bn = bias[nt * 16 + l16];
            #pragma unroll
            for (int i = 0; i < 4; ++i) {
                int mm = mbase + mi * 16 + quad * 4 + i;
                if (mm < N_OUT_) {
                    float v = acc[mi][nt][i] + bn;
                    v = (v > 0.0f) ? v : expm1f(v);
                    __builtin_nontemporal_store(v, &outb[(size_t)mm * C_ + nt * 16 + l16]);
                }
            }
        }
    }
}

extern "C" void kernel_launch(void* const* d_in, const int* in_sizes, int n_in,
                              void* d_out, int out_size, void* d_ws, size_t ws_size,
                              hipStream_t stream) {
    const float* x      = (const float*)d_in[0];
    const float* tvals  = (const float*)d_in[1];
    const int*   trow   = (const int*)d_in[2];
    const int*   tcol   = (const int*)d_in[3];
    const int*   spiral = (const int*)d_in[4];
    const float* W      = (const float*)d_in[5];
    const float* bias   = (const float*)d_in[6];
    float* out = (float*)d_out;

    char* ws = (char*)d_ws;
    size_t off = 0;
    auto alloc = [&](size_t bytes) -> void* {
        void* p = ws + off;
        off += (bytes + 255) & ~(size_t)255;
        return p;
    };
    __bf16* pooled  = (__bf16*)alloc((size_t)B_ * N_OUT_ * C_ * 2);   // 51.2 MB
    __bf16* WtF     = (__bf16*)alloc(72 * 64 * 8 * 2);
    int*    cursor  = (int*)alloc(N_OUT_ * 4);
    int*    offsets = (int*)alloc((N_OUT_ + 1) * 4);
    int*    ecol    = (int*)alloc(NNZ_ * 4);
    float*  eval    = (float*)alloc(NNZ_ * 4);
    int*    counts  = (int*)alloc(N_OUT_ * 4);
    int*    bsum    = (int*)alloc(32 * 4);

    const int NBLK = (N_OUT_ + 1023) / 1024;   // 25
    init_kernel<<<(72 * 64 * 8 + 255) / 256, 256, 0, stream>>>(W, WtF, counts);
    hist_kernel<<<(NNZ_ + 255) / 256, 256, 0, stream>>>(trow, counts, NNZ_);
    scan1_kernel<<<NBLK, 1024, 0, stream>>>(counts, offsets, bsum, N_OUT_);
    scan2_kernel<<<1, 64, 0, stream>>>(bsum, offsets, NBLK, N_OUT_);
    scan3_kernel<<<NBLK, 1024, 0, stream>>>(offsets, bsum, cursor, N_OUT_);
    fill_kernel<<<(NNZ_ + 255) / 256, 256, 0, stream>>>(trow, tcol, tvals, cursor, ecol, eval, NNZ_);
    pool_kernel<<<8 * (N_OUT_ / 8), 256, 0, stream>>>(x, offsets, ecol, eval, pooled);
    gemm_kernel<<<8 * (2 * MT2_), 256, 0, stream>>>(pooled, spiral, WtF, bias, out);
}

// Round 13
// 270.662 us; speedup vs baseline: 2.7620x; 1.0786x over previous
//
#include <hip/hip_runtime.h>

#define B_     16
#define N_IN_  6250
#define N_OUT_ 25000
#define C_     64
#define S_     9
#define NNZ_   75000
#define MT2_   98           // ceil(N_OUT/256)

typedef __bf16 bf16x8 __attribute__((ext_vector_type(8)));
typedef __bf16 bf16x4 __attribute__((ext_vector_type(4)));
typedef float floatx4 __attribute__((ext_vector_type(4)));

__device__ inline void async_copy16(const void* g, void* l) {
    __builtin_amdgcn_global_load_lds(
        (const __attribute__((address_space(1))) void*)g,
        (__attribute__((address_space(3))) void*)l, 16, 0, 0);
}

// ---------------- init: zero counts + W -> WtF (one node) ----------------
// WtF[(kb*64 + n)*8 + j] = W[(kb*8 + j)*64 + n], kb = k/8 in [0,72).
__global__ void init_kernel(const float* __restrict__ W, __bf16* __restrict__ WtF,
                            int* __restrict__ counts) {
    int i = blockIdx.x * blockDim.x + threadIdx.x;
    if (i < N_OUT_) counts[i] = 0;
    if (i < 72 * 64 * 8) {
        int kb = i >> 9;
        int n  = (i >> 3) & 63;
        int j  = i & 7;
        WtF[i] = (__bf16)W[(kb * 8 + j) * 64 + n];
    }
}

// ---------------- CSR build (R2-proven chain) ----------------

__global__ void hist_kernel(const int* __restrict__ rows, int* __restrict__ counts, int nnz) {
    int i = blockIdx.x * blockDim.x + threadIdx.x;
    if (i < nnz) atomicAdd(&counts[rows[i]], 1);
}

__global__ void scan1_kernel(const int* __restrict__ counts, int* __restrict__ offsets,
                             int* __restrict__ bsum, int n) {
    __shared__ int wsum[16];
    int t = threadIdx.x;
    int wid = t >> 6, lane = t & 63;
    int i = blockIdx.x * 1024 + t;
    int v = (i < n) ? counts[i] : 0;
    int s = v;
    #pragma unroll
    for (int d = 1; d < 64; d <<= 1) {
        int u = __shfl_up(s, d, 64);
        if (lane >= d) s += u;
    }
    if (lane == 63) wsum[wid] = s;
    __syncthreads();
    if (wid == 0 && lane < 16) {
        int ws = wsum[lane];
        #pragma unroll
        for (int d = 1; d < 16; d <<= 1) {
            int u = __shfl_up(ws, d, 64);
            if (lane >= d) ws += u;
        }
        wsum[lane] = ws;
    }
    __syncthreads();
    int wave_off = (wid == 0) ? 0 : wsum[wid - 1];
    int incl = s + wave_off;
    if (i < n) offsets[i] = incl - v;
    if (t == 1023) bsum[blockIdx.x] = incl;
}

__global__ void scan2_kernel(int* __restrict__ bsum, int* __restrict__ offsets, int nblk, int n) {
    if (threadIdx.x == 0) {
        int t = 0;
        for (int i = 0; i < nblk; ++i) { int v = bsum[i]; bsum[i] = t; t += v; }
        offsets[n] = t;
    }
}

__global__ void scan3_kernel(int* __restrict__ offsets, const int* __restrict__ bsum,
                             int* __restrict__ cursor, int n) {
    int i = blockIdx.x * 1024 + threadIdx.x;
    if (i < n) {
        int o = offsets[i] + bsum[blockIdx.x];
        offsets[i] = o;
        cursor[i] = o;
    }
}

__global__ void fill_kernel(const int* __restrict__ rows, const int* __restrict__ cols,
                            const float* __restrict__ vals, int* __restrict__ cursor,
                            int* __restrict__ ecol, float* __restrict__ eval, int nnz) {
    int i = blockIdx.x * blockDim.x + threadIdx.x;
    if (i < nnz) {
        int p = atomicAdd(&cursor[rows[i]], 1);
        ecol[p] = cols[i];
        eval[p] = vals[i];
    }
}

// ---------------- pooling: XCD-affine, float4 lanes (R12) ----------------
__global__ __launch_bounds__(256) void pool_kernel(
        const float* __restrict__ x, const int* __restrict__ offsets,
        const int* __restrict__ ecol, const float* __restrict__ eval,
        __bf16* __restrict__ pooled) {
    int bx = blockIdx.x;
    int xcd = bx & 7;
    int rg = bx >> 3;                      // 0..3124 -> rows rg*8 .. rg*8+7
    int t = threadIdx.x;
    int wid = t >> 6, lane = t & 63;
    int r2  = lane >> 5;                   // which of the wave's 2 rows
    int b   = xcd + 8 * ((lane >> 4) & 1); // which of the XCD's 2 batches
    int l16 = lane & 15;                   // float4 slot within the row
    int row = rg * 8 + wid * 2 + r2;

    const float* xb = x + (size_t)b * N_IN_ * C_ + l16 * 4;
    int beg = offsets[row], end = offsets[row + 1];

    floatx4 acc = {};
    int col = 0; float v = 0.f;
    if (beg < end) { col = ecol[beg]; v = eval[beg]; }
    for (int k = beg; k < end; ++k) {
        int col2 = 0; float v2 = 0.f;
        if (k + 1 < end) { col2 = ecol[k + 1]; v2 = eval[k + 1]; }
        acc += *reinterpret_cast<const floatx4*>(xb + (size_t)col * C_) * v;
        col = col2; v = v2;
    }

    bf16x4 o;
    #pragma unroll
    for (int j = 0; j < 4; ++j) o[j] = (__bf16)acc[j];
    *reinterpret_cast<bf16x4*>(pooled + ((size_t)b * N_OUT_ + row) * C_ + l16 * 4) = o;
}

// ---------------- spiral gather + GEMM + bias + ELU -------------------------
// NEW: full-line gather staging. Each global_load_lds instruction reads
// 8 rows x 128B FULL L2 LINES (8 segments) instead of the register-gather's
// 16 rows x 64B (16 segments) — halves the outstanding-miss count the
// per-CU miss queue must sustain, which 6 falsified variants identify as
// the wall. A rows land in LDS (linear dest, XOR-swizzled global source,
// matching XOR on ds_read; both-sides rule 21; 2-way banks = free m136).
// Per step: stage A(32KB)+W(8KB) for s+1, ds_read frags of s, 32 MFMA/wave,
// barrier. LDS 80KB -> 2 blocks/CU. XCD-affine batches as before.
__global__ __launch_bounds__(256, 2) void gemm_kernel(
        const __bf16* __restrict__ pooled, const int* __restrict__ spiral,
        const __bf16* __restrict__ WtF, const float* __restrict__ bias,
        float* __restrict__ out) {
    __shared__ __bf16 As[2][256 * 64];   // 2 x 32KB (256 gathered rows/step)
    __shared__ __bf16 Ws[2][4096];       // 2 x 8KB  (per-step W slice)

    int bx = blockIdx.x;
    int xcd = bx & 7;
    int rr = bx >> 3;                    // 0..2*MT2_-1
    int half = (rr >= MT2_) ? 1 : 0;
    int mt = rr - half * MT2_;           // 0..97
    int b = xcd + 8 * half;

    int t = threadIdx.x;
    int wave = t >> 6, lane = t & 63;
    int quad = lane >> 4, l16 = lane & 15;
    int mbase = mt * 256;

    const __bf16* poolb = pooled + (size_t)b * N_OUT_ * C_;

    int r0 = t >> 3;                     // this thread's base staging row
    int cw = t & 7;                      // linear LDS slot within the row

    // stage step s into buffer d: 8 A-passes (8 rows x 128B lines each) + 2 W
    auto stage = [&](int s, int d) {
        #pragma unroll
        for (int p = 0; p < 8; ++p) {
            int r = r0 + p * 32;                 // 0..255
            int m = mbase + r;
            int mc = (m < N_OUT_) ? m : 0;
            int sp = spiral[mc * S_ + s];        // gathered pooled row
            int gc = cw ^ (r & 7);               // pre-swizzled source chunk
            async_copy16((const char*)poolb + ((size_t)sp << 7) + (gc << 4),
                         (char*)&As[d][0] + (((r << 3) + cw) << 4));
        }
        #pragma unroll
        for (int p = 0; p < 2; ++p) {
            int c = t + p * 256;
            async_copy16((const char*)WtF + (size_t)s * 8192 + (c << 4),
                         (char*)&Ws[d][0] + (c << 4));
        }
    };

    stage(0, 0);
    __syncthreads();   // buffer 0 ready

    floatx4 acc[4][4] = {};

    #pragma unroll
    for (int s = 0; s < S_; ++s) {
        int cur = s & 1;
        if (s + 1 < S_) stage(s + 1, cur ^ 1);

        // W fragments from slice: elem = ((kc*4+quad)*64 + nt*16 + l16)*8
        bf16x8 wf[4][2];
        #pragma unroll
        for (int kc = 0; kc < 2; ++kc)
            #pragma unroll
            for (int nt = 0; nt < 4; ++nt)
                wf[nt][kc] = *reinterpret_cast<const bf16x8*>(
                    &Ws[cur][((((kc << 2) + quad) << 6) | (nt << 4) | l16) << 3]);

        // A fragments: row r = wave*64+mi*16+l16, chunk F = kc*4+quad at F^(r&7)
        bf16x8 af[4][2];
        #pragma unroll
        for (int mi = 0; mi < 4; ++mi) {
            int r = (wave << 6) + (mi << 4) + l16;
            #pragma unroll
            for (int kc = 0; kc < 2; ++kc) {
                int F = (kc << 2) + quad;
                af[mi][kc] = *reinterpret_cast<const bf16x8*>(
                    &As[cur][(r << 6) + ((F ^ (l16 & 7)) << 3)]);
            }
        }

        #pragma unroll
        for (int kc = 0; kc < 2; ++kc)
            #pragma unroll
            for (int nt = 0; nt < 4; ++nt)
                #pragma unroll
                for (int mi = 0; mi < 4; ++mi)
                    acc[mi][nt] = __builtin_amdgcn_mfma_f32_16x16x32_bf16(
                        af[mi][kc], wf[nt][kc], acc[mi][nt], 0, 0, 0);

        __syncthreads();   // drains stage(s+1); buffers swap
    }

    // epilogue: D[m = quad*4 + i][n = l16] per (mi, nt) tile, nontemporal
    float* outb = out + (size_t)b * N_OUT_ * C_;
    #pragma unroll
    for (int mi = 0; mi < 4; ++mi) {
        #pragma unroll
        for (int nt = 0; nt < 4; ++nt) {
            float bn = bias[(nt << 4) + l16];
            #pragma unroll
            for (int i = 0; i < 4; ++i) {
                int mm = mbase + (wave << 6) + (mi << 4) + (quad << 2) + i;
                if (mm < N_OUT_) {
                    float v = acc[mi][nt][i] + bn;
                    v = (v > 0.0f) ? v : expm1f(v);
                    __builtin_nontemporal_store(v, &outb[(size_t)mm * C_ + (nt << 4) + l16]);
                }
            }
        }
    }
}

extern "C" void kernel_launch(void* const* d_in, const int* in_sizes, int n_in,
                              void* d_out, int out_size, void* d_ws, size_t ws_size,
                              hipStream_t stream) {
    const float* x      = (const float*)d_in[0];
    const float* tvals  = (const float*)d_in[1];
    const int*   trow   = (const int*)d_in[2];
    const int*   tcol   = (const int*)d_in[3];
    const int*   spiral = (const int*)d_in[4];
    const float* W      = (const float*)d_in[5];
    const float* bias   = (const float*)d_in[6];
    float* out = (float*)d_out;

    char* ws = (char*)d_ws;
    size_t off = 0;
    auto alloc = [&](size_t bytes) -> void* {
        void* p = ws + off;
        off += (bytes + 255) & ~(size_t)255;
        return p;
    };
    __bf16* pooled  = (__bf16*)alloc((size_t)B_ * N_OUT_ * C_ * 2);   // 51.2 MB
    __bf16* WtF     = (__bf16*)alloc(72 * 64 * 8 * 2);
    int*    cursor  = (int*)alloc(N_OUT_ * 4);
    int*    offsets = (int*)alloc((N_OUT_ + 1) * 4);
    int*    ecol    = (int*)alloc(NNZ_ * 4);
    float*  eval    = (float*)alloc(NNZ_ * 4);
    int*    counts  = (int*)alloc(N_OUT_ * 4);
    int*    bsum    = (int*)alloc(32 * 4);

    const int NBLK = (N_OUT_ + 1023) / 1024;   // 25
    init_kernel<<<(72 * 64 * 8 + 255) / 256, 256, 0, stream>>>(W, WtF, counts);
    hist_kernel<<<(NNZ_ + 255) / 256, 256, 0, stream>>>(trow, counts, NNZ_);
    scan1_kernel<<<NBLK, 1024, 0, stream>>>(counts, offsets, bsum, N_OUT_);
    scan2_kernel<<<1, 64, 0, stream>>>(bsum, offsets, NBLK, N_OUT_);
    scan3_kernel<<<NBLK, 1024, 0, stream>>>(offsets, bsum, cursor, N_OUT_);
    fill_kernel<<<(NNZ_ + 255) / 256, 256, 0, stream>>>(trow, tcol, tvals, cursor, ecol, eval, NNZ_);
    pool_kernel<<<8 * (N_OUT_ / 8), 256, 0, stream>>>(x, offsets, ecol, eval, pooled);
    gemm_kernel<<<8 * (2 * MT2_), 256, 0, stream>>>(pooled, spiral, WtF, bias, out);
}